// Round 3
// baseline (3706.316 us; speedup 1.0000x reference)
//
#include <hip/hip_runtime.h>
#include <hip/hip_bf16.h>

typedef unsigned short ushort_t;
typedef unsigned int uint_t;

typedef float f32x4 __attribute__((ext_vector_type(4)));
typedef short s16x8 __attribute__((ext_vector_type(8)));

#define HW 56
#define NTOK 3136           // 56*56
#define CDIM 512
#define NHEAD 8
#define CH 64
#define QKVC 1536
#define HID 2048

__device__ __forceinline__ float b2f(ushort_t u) {
    union { uint_t i; float f; } cv; cv.i = ((uint_t)u) << 16; return cv.f;
}
__device__ __forceinline__ ushort_t f2b(float f) {
    union { __hip_bfloat16 h; ushort_t u; } cv; cv.h = __float2bfloat16(f); return cv.u;
}
__device__ __forceinline__ uint_t pk2(float a, float b) {
    return (uint_t)f2b(a) | ((uint_t)f2b(b) << 16);
}

// ---------------- transpose W[K][N] (fp32) -> Wt[N][K] (bf16) ----------------
__global__ __launch_bounds__(256) void k_transpose(const float* __restrict__ in,
                                                   ushort_t* __restrict__ out,
                                                   int K, int Npr) {
    __shared__ float tile[32][33];
    int tx = threadIdx.x & 31, ty = threadIdx.x >> 5;   // ty 0..7
    int kb = blockIdx.y * 32, nb = blockIdx.x * 32;
#pragma unroll
    for (int i = 0; i < 4; i++)
        tile[ty + i * 8][tx] = in[(size_t)(kb + ty + i * 8) * Npr + nb + tx];
    __syncthreads();
#pragma unroll
    for (int i = 0; i < 4; i++)
        out[(size_t)(nb + ty + i * 8) * K + kb + tx] = f2b(tile[tx][ty + i * 8]);
}

// ---------------- ConvPosEnc: x0 = dwconv3x3(x) + b + x  (all fp32) ----------------
__global__ __launch_bounds__(256) void k_cpe(const float* __restrict__ x,
                                             const float* __restrict__ w,
                                             const float* __restrict__ bias,
                                             float* __restrict__ x0) {
    int n = blockIdx.x, b = blockIdx.y;
    int y = n / HW, xx = n % HW;
    size_t bb = (size_t)b * NTOK * CDIM;
    for (int c = threadIdx.x; c < CDIM; c += 256) {
        float acc = 0.f;
#pragma unroll
        for (int ky = 0; ky < 3; ky++) {
            int yy = y + ky - 1; if (yy < 0 || yy >= HW) continue;
#pragma unroll
            for (int kx = 0; kx < 3; kx++) {
                int xb = xx + kx - 1; if (xb < 0 || xb >= HW) continue;
                acc += w[c * 9 + ky * 3 + kx] * x[bb + (size_t)(yy * HW + xb) * CDIM + c];
            }
        }
        x0[bb + (size_t)n * CDIM + c] = acc + bias[c] + x[bb + (size_t)n * CDIM + c];
    }
}

// -------- LayerNorm over C=512: fp32 in -> bf16 out, one wave per row --------
__global__ __launch_bounds__(256) void k_ln(const float* __restrict__ in,
                                            const float* __restrict__ w,
                                            const float* __restrict__ b,
                                            ushort_t* __restrict__ out) {
    int wid = threadIdx.x >> 6, lane = threadIdx.x & 63;
    size_t row = (size_t)blockIdx.x * 4 + wid;
    const float* p = in + row * CDIM + lane * 8;
    float4 v0 = *(const float4*)p;
    float4 v1 = *(const float4*)(p + 4);
    float v[8] = { v0.x, v0.y, v0.z, v0.w, v1.x, v1.y, v1.z, v1.w };
    float s = 0.f, s2 = 0.f;
#pragma unroll
    for (int i = 0; i < 8; i++) { s += v[i]; s2 += v[i] * v[i]; }
#pragma unroll
    for (int m = 1; m < 64; m <<= 1) { s += __shfl_xor(s, m); s2 += __shfl_xor(s2, m); }
    float mean = s * (1.f / CDIM);
    float var = s2 * (1.f / CDIM) - mean * mean;
    float rstd = rsqrtf(var + 1e-6f);
    float4 w0 = *(const float4*)(w + lane * 8);
    float4 w1 = *(const float4*)(w + lane * 8 + 4);
    float4 b0 = *(const float4*)(b + lane * 8);
    float4 b1 = *(const float4*)(b + lane * 8 + 4);
    float wv[8] = { w0.x, w0.y, w0.z, w0.w, w1.x, w1.y, w1.z, w1.w };
    float bv[8] = { b0.x, b0.y, b0.z, b0.w, b1.x, b1.y, b1.z, b1.w };
    float o[8];
#pragma unroll
    for (int i = 0; i < 8; i++) o[i] = (v[i] - mean) * rstd * wv[i] + bv[i];
    uint4 ro;
    ro.x = pk2(o[0], o[1]); ro.y = pk2(o[2], o[3]); ro.z = pk2(o[4], o[5]); ro.w = pk2(o[6], o[7]);
    *(uint4*)(out + row * CDIM + lane * 8) = ro;
}

// ------------- MFMA GEMM: out[M,N] = A[M,K] @ Bt[N,K]^T  (A,Bt bf16) -------------
// EPI 0: store bf16.  EPI 1: +bias +res(fp32), store fp32.  EPI 2: +bias, GELU, store bf16.
template <int EPI>
__global__ __launch_bounds__(256) void k_gemm(const ushort_t* __restrict__ A,
                                              const ushort_t* __restrict__ Bt,
                                              const float* __restrict__ bias,
                                              const float* __restrict__ res,
                                              void* __restrict__ outv,
                                              int M, int Npr, int K) {
    __shared__ ushort_t As[128 * 72];
    __shared__ ushort_t Bs[128 * 72];
    int t = threadIdx.x;
    int m0 = blockIdx.y * 128, n0 = blockIdx.x * 128;
    int wid = t >> 6, lane = t & 63, q = lane >> 4, r16 = lane & 15;
    int wr = wid >> 1, wc = wid & 1;
    f32x4 acc[4][4] = {};
    int rowA = t >> 3, kc = (t & 7) * 8;
    const ushort_t* pAp[4];
    const ushort_t* pBp[4];
#pragma unroll
    for (int p4 = 0; p4 < 4; p4++) {
        int ra = m0 + rowA + p4 * 32; if (ra > M - 1) ra = M - 1;
        pAp[p4] = A + (size_t)ra * K + kc;
        pBp[p4] = Bt + (size_t)(n0 + rowA + p4 * 32) * K + kc;
    }

    for (int k0 = 0; k0 < K; k0 += 64) {
#pragma unroll
        for (int p4 = 0; p4 < 4; p4++) {
            uint4 va = *(const uint4*)(pAp[p4] + k0);
            uint4 vb = *(const uint4*)(pBp[p4] + k0);
            *(uint4*)&As[(rowA + p4 * 32) * 72 + kc] = va;
            *(uint4*)&Bs[(rowA + p4 * 32) * 72 + kc] = vb;
        }
        __syncthreads();
#pragma unroll
        for (int kk = 0; kk < 64; kk += 32) {
            s16x8 a[4], b[4];
#pragma unroll
            for (int i = 0; i < 4; i++) {
                a[i] = *(const s16x8*)&As[(wr * 64 + i * 16 + r16) * 72 + kk + q * 8];
                b[i] = *(const s16x8*)&Bs[(wc * 64 + i * 16 + r16) * 72 + kk + q * 8];
            }
#pragma unroll
            for (int mi = 0; mi < 4; mi++)
#pragma unroll
                for (int ni = 0; ni < 4; ni++)
                    acc[mi][ni] = __builtin_amdgcn_mfma_f32_16x16x32_bf16(a[mi], b[ni], acc[mi][ni], 0, 0, 0);
        }
        __syncthreads();
    }

#pragma unroll
    for (int mi = 0; mi < 4; mi++) {
#pragma unroll
        for (int ni = 0; ni < 4; ni++) {
            int col = n0 + wc * 64 + ni * 16 + r16;
            float bv = 0.f;
            if (EPI != 0) bv = bias[col];
#pragma unroll
            for (int r = 0; r < 4; r++) {
                int row = m0 + wr * 64 + mi * 16 + q * 4 + r;
                if (row >= M) continue;
                float xv = acc[mi][ni][r];
                size_t idx = (size_t)row * Npr + col;
                if (EPI == 0) {
                    ((ushort_t*)outv)[idx] = f2b(xv);
                } else if (EPI == 1) {
                    ((float*)outv)[idx] = xv + bv + res[idx];
                } else {
                    xv += bv;
                    xv = 0.5f * xv * (1.f + erff(xv * 0.70710678118654752f));
                    ((ushort_t*)outv)[idx] = f2b(xv);
                }
            }
        }
    }
}

// ------------- softmax stats over tokens: per (b, channel) max & sum(exp) -------------
__global__ __launch_bounds__(256) void k_softmax_stats(const ushort_t* __restrict__ qkv,
                                                       float* __restrict__ Mx,
                                                       float* __restrict__ Sx) {
    int b = blockIdx.y, c0 = blockIdx.x * 64;
    int ch = threadIdx.x & 63, nt = threadIdx.x >> 6;
    const ushort_t* base = qkv + (size_t)b * NTOK * QKVC + CDIM + c0 + ch;
    __shared__ float red[4][64];
    float mx = -1e30f;
    for (int n = nt; n < NTOK; n += 4) mx = fmaxf(mx, b2f(base[(size_t)n * QKVC]));
    red[nt][ch] = mx;
    __syncthreads();
    if (nt == 0) {
        mx = fmaxf(fmaxf(red[0][ch], red[1][ch]), fmaxf(red[2][ch], red[3][ch]));
        red[0][ch] = mx;
    }
    __syncthreads();
    mx = red[0][ch];
    __syncthreads();
    float s = 0.f;
    for (int n = nt; n < NTOK; n += 4) s += __expf(b2f(base[(size_t)n * QKVC]) - mx);
    red[nt][ch] = s;
    __syncthreads();
    if (nt == 0) {
        s = red[0][ch] + red[1][ch] + red[2][ch] + red[3][ch];
        Mx[b * CDIM + c0 + ch] = mx;
        Sx[b * CDIM + c0 + ch] = s;
    }
}

// ------------- kv[b,h] = scale * softmax(k)^T @ v  (64x64 fp32) -------------
__global__ __launch_bounds__(256) void k_kv(const ushort_t* __restrict__ qkv,
                                            const float* __restrict__ Mx,
                                            const float* __restrict__ Sx,
                                            float* __restrict__ kv) {
    int hd = blockIdx.x, b = blockIdx.y;
    int c0 = hd * CH;
    int t = threadIdx.x, tx = t & 15, ty = t >> 4;
    __shared__ float mx[64];
    __shared__ float ek[8][64];
    __shared__ float vv[8][64];
    if (t < 64) mx[t] = Mx[b * CDIM + c0 + t];
    __syncthreads();
    float acc[4][4] = {};
    const ushort_t* kbase = qkv + (size_t)b * NTOK * QKVC + CDIM + c0;
    const ushort_t* vbase = kbase + CDIM;
    for (int n0 = 0; n0 < NTOK; n0 += 8) {
        for (int idx = t; idx < 512; idx += 256) {
            int r = idx >> 6, ch = idx & 63;
            ek[r][ch] = __expf(b2f(kbase[(size_t)(n0 + r) * QKVC + ch]) - mx[ch]);
            vv[r][ch] = b2f(vbase[(size_t)(n0 + r) * QKVC + ch]);
        }
        __syncthreads();
#pragma unroll
        for (int r = 0; r < 8; r++) {
            float ekv[4], vvv[4];
#pragma unroll
            for (int i = 0; i < 4; i++) ekv[i] = ek[r][ty * 4 + i];
#pragma unroll
            for (int j = 0; j < 4; j++) vvv[j] = vv[r][tx * 4 + j];
#pragma unroll
            for (int i = 0; i < 4; i++)
#pragma unroll
                for (int j = 0; j < 4; j++) acc[i][j] += ekv[i] * vvv[j];
        }
        __syncthreads();
    }
    const float scale = 0.125f;   // Ch^-0.5, folded here
    float* outp = kv + (size_t)(b * NHEAD + hd) * CH * CH;
#pragma unroll
    for (int i = 0; i < 4; i++) {
        float sinv = scale / Sx[b * CDIM + c0 + ty * 4 + i];
#pragma unroll
        for (int j = 0; j < 4; j++)
            outp[(size_t)(ty * 4 + i) * CH + tx * 4 + j] = acc[i][j] * sinv;
    }
}

// ------------- ConvRelPosEnc: grouped depthwise 3/5/7 conv on v (weights fp32) -------------
__global__ __launch_bounds__(256) void k_convv(const ushort_t* __restrict__ qkv,
                                               const float* __restrict__ w3, const float* __restrict__ b3,
                                               const float* __restrict__ w5, const float* __restrict__ b5,
                                               const float* __restrict__ w7, const float* __restrict__ b7,
                                               ushort_t* __restrict__ conv) {
    int n = blockIdx.x, b = blockIdx.y;
    int y = n / HW, x = n % HW;
    const ushort_t* vbase = qkv + (size_t)b * NTOK * QKVC + 2 * CDIM;
    for (int c = threadIdx.x; c < CDIM; c += 256) {
        const float* wp; float acc; int ks, pad;
        if (c < 128)       { wp = w3 + c * 9;          acc = b3[c];       ks = 3; pad = 1; }
        else if (c < 320)  { wp = w5 + (c - 128) * 25; acc = b5[c - 128]; ks = 5; pad = 2; }
        else               { wp = w7 + (c - 320) * 49; acc = b7[c - 320]; ks = 7; pad = 3; }
        for (int ky = 0; ky < ks; ky++) {
            int yy = y + ky - pad; if (yy < 0 || yy >= HW) continue;
            for (int kx = 0; kx < ks; kx++) {
                int xb = x + kx - pad; if (xb < 0 || xb >= HW) continue;
                acc += wp[ky * ks + kx] * b2f(vbase[(size_t)(yy * HW + xb) * QKVC + c]);
            }
        }
        conv[((size_t)b * NTOK + n) * CDIM + c] = f2b(acc);
    }
}

// ------------- attn = q @ kv + q * conv_v  (overwrites conv buffer, bf16) -------------
__global__ __launch_bounds__(256) void k_attn(const ushort_t* __restrict__ qkv,
                                              const float* __restrict__ kv,
                                              ushort_t* __restrict__ conv) {
    int nb = blockIdx.x, hd = blockIdx.y, b = blockIdx.z;
    int t = threadIdx.x, tx = t & 15, ty = t >> 4;   // ty 0..15
    __shared__ float kvl[64 * 64];    // [ck][cv]
    __shared__ float ql[64 * 65];     // [row][ck], padded
    const float* kvsrc = kv + (size_t)(b * NHEAD + hd) * CH * CH;
    for (int idx = t; idx < 4096; idx += 256) kvl[idx] = kvsrc[idx];
    const ushort_t* qbase = qkv + ((size_t)b * NTOK + nb * 64) * QKVC + hd * CH;
    for (int idx = t; idx < 4096; idx += 256) {
        int r = idx >> 6, ck = idx & 63;
        ql[r * 65 + ck] = b2f(qbase[(size_t)r * QKVC + ck]);
    }
    __syncthreads();
    float acc[4][4] = {};
    for (int ck = 0; ck < 64; ck++) {
        float kvr[4];
#pragma unroll
        for (int j = 0; j < 4; j++) kvr[j] = kvl[ck * 64 + tx * 4 + j];
#pragma unroll
        for (int i = 0; i < 4; i++) {
            float qv = ql[(ty + 16 * i) * 65 + ck];
#pragma unroll
            for (int j = 0; j < 4; j++) acc[i][j] += qv * kvr[j];
        }
    }
    size_t obase = (size_t)b * NTOK + nb * 64;
#pragma unroll
    for (int i = 0; i < 4; i++) {
        int row = ty + 16 * i;
        size_t o = (obase + row) * CDIM + hd * CH + tx * 4;
#pragma unroll
        for (int j = 0; j < 4; j++) {
            float qv = ql[row * 65 + tx * 4 + j];
            float cvv = b2f(conv[o + j]);
            conv[o + j] = f2b(acc[i][j] + qv * cvv);
        }
    }
}

// ---------------------------------------------------------------------------
extern "C" void kernel_launch(void* const* d_in, const int* in_sizes, int n_in,
                              void* d_out, int out_size, void* d_ws, size_t ws_size,
                              hipStream_t stream) {
    const float* x     = (const float*)d_in[0];
    const float* cpe_w = (const float*)d_in[3];
    const float* cpe_b = (const float*)d_in[4];
    const float* ln1_w = (const float*)d_in[5];
    const float* ln1_b = (const float*)d_in[6];
    const float* qkv_w = (const float*)d_in[7];
    const float* proj_w = (const float*)d_in[8];
    const float* proj_b = (const float*)d_in[9];
    const float* w3 = (const float*)d_in[10];
    const float* b3 = (const float*)d_in[11];
    const float* w5 = (const float*)d_in[12];
    const float* b5 = (const float*)d_in[13];
    const float* w7 = (const float*)d_in[14];
    const float* b7 = (const float*)d_in[15];
    const float* ln2_w = (const float*)d_in[16];
    const float* ln2_b = (const float*)d_in[17];
    const float* fc1_w = (const float*)d_in[18];
    const float* fc1_b = (const float*)d_in[19];
    const float* fc2_w = (const float*)d_in[20];
    const float* fc2_b = (const float*)d_in[21];
    float* out = (float*)d_out;

    char* p = (char*)d_ws;
    ushort_t* wt_qkv  = (ushort_t*)p; p += (size_t)QKVC * CDIM * 2;
    ushort_t* wt_proj = (ushort_t*)p; p += (size_t)CDIM * CDIM * 2;
    ushort_t* wt_fc1  = (ushort_t*)p; p += (size_t)HID * CDIM * 2;
    ushort_t* wt_fc2  = (ushort_t*)p; p += (size_t)CDIM * HID * 2;
    size_t wt_bytes = (size_t)(p - (char*)d_ws);

    k_transpose<<<dim3(QKVC / 32, CDIM / 32), 256, 0, stream>>>(qkv_w, wt_qkv, CDIM, QKVC);
    k_transpose<<<dim3(CDIM / 32, CDIM / 32), 256, 0, stream>>>(proj_w, wt_proj, CDIM, CDIM);
    k_transpose<<<dim3(HID / 32, CDIM / 32), 256, 0, stream>>>(fc1_w, wt_fc1, CDIM, HID);
    k_transpose<<<dim3(CDIM / 32, HID / 32), 256, 0, stream>>>(fc2_w, wt_fc2, HID, CDIM);

    // per-batch bytes: cur(bf16) + union{conv+qkvb | hid}(bf16) + kv + stats
    const size_t per_b = (size_t)NTOK * CDIM * 2
                       + (size_t)NTOK * HID * 2
                       + (size_t)NHEAD * CH * CH * 4
                       + (size_t)CDIM * 4 * 2;
    int Bc = 16;
    while (Bc > 1 && wt_bytes + (size_t)Bc * per_b > ws_size) Bc >>= 1;

    ushort_t* cur = (ushort_t*)p; p += (size_t)Bc * NTOK * CDIM * 2;
    char* un = p;                 p += (size_t)Bc * NTOK * HID * 2;
    ushort_t* conv = (ushort_t*)un;
    ushort_t* qkvb = (ushort_t*)(un + (size_t)Bc * NTOK * CDIM * 2);
    ushort_t* hid  = (ushort_t*)un;
    float* kvb = (float*)p; p += (size_t)Bc * NHEAD * CH * CH * 4;
    float* Mx  = (float*)p; p += (size_t)Bc * CDIM * 4;
    float* Sx  = (float*)p;

    for (int b0 = 0; b0 < 16; b0 += Bc) {
        int M = Bc * NTOK;
        int gy = (M + 127) / 128;
        const float* xch = x + (size_t)b0 * NTOK * CDIM;
        float* och = out + (size_t)b0 * NTOK * CDIM;
        float* x0 = och;   // fp32 residual backbone lives in the output chunk

        k_cpe<<<dim3(NTOK, Bc), 256, 0, stream>>>(xch, cpe_w, cpe_b, x0);
        k_ln<<<M / 4, 256, 0, stream>>>(x0, ln1_w, ln1_b, cur);
        k_gemm<0><<<dim3(QKVC / 128, gy), 256, 0, stream>>>(cur, wt_qkv, nullptr, nullptr, qkvb, M, QKVC, CDIM);
        k_softmax_stats<<<dim3(8, Bc), 256, 0, stream>>>(qkvb, Mx, Sx);
        k_kv<<<dim3(NHEAD, Bc), 256, 0, stream>>>(qkvb, Mx, Sx, kvb);
        k_convv<<<dim3(NTOK, Bc), 256, 0, stream>>>(qkvb, w3, b3, w5, b5, w7, b7, conv);
        k_attn<<<dim3(NTOK / 64, NHEAD, Bc), 256, 0, stream>>>(qkvb, kvb, conv);
        k_gemm<1><<<dim3(CDIM / 128, gy), 256, 0, stream>>>(conv, wt_proj, proj_b, x0, x0, M, CDIM, CDIM);
        k_ln<<<M / 4, 256, 0, stream>>>(x0, ln2_w, ln2_b, cur);
        k_gemm<2><<<dim3(HID / 128, gy), 256, 0, stream>>>(cur, wt_fc1, fc1_b, nullptr, hid, M, HID, CDIM);
        k_gemm<1><<<dim3(CDIM / 128, gy), 256, 0, stream>>>(hid, wt_fc2, fc2_b, x0, och, M, CDIM, HID);
    }
}

// Round 4
// 2044.356 us; speedup vs baseline: 1.8130x; 1.8130x over previous
//
#include <hip/hip_runtime.h>
#include <hip/hip_bf16.h>

typedef unsigned short ushort_t;
typedef unsigned int uint_t;

typedef float f32x4 __attribute__((ext_vector_type(4)));
typedef short s16x8 __attribute__((ext_vector_type(8)));

#define HW 56
#define NTOK 3136           // 56*56
#define CDIM 512
#define NHEAD 8
#define CH 64
#define QKVC 1536
#define HID 2048

// packed tap-major weight buffer layout (floats):
// [0,4608)      cpe 3x3:  [i*512 + c]           i<9,  c<512
// [4608,5760)   crpe 3x3: [4608 + i*128 + c]    i<9,  c<128
// [5760,10560)  crpe 5x5: [5760 + i*192 + c]    i<25, c<192
// [10560,19968) crpe 7x7: [10560 + i*192 + c]   i<49, c<192
// [19968,19976) zeros (zero-page for OOB loads)
#define WPK_TOTAL 19976

__device__ __forceinline__ float b2f(ushort_t u) {
    union { uint_t i; float f; } cv; cv.i = ((uint_t)u) << 16; return cv.f;
}
__device__ __forceinline__ ushort_t f2b(float f) {
    union { __hip_bfloat16 h; ushort_t u; } cv; cv.h = __float2bfloat16(f); return cv.u;
}
__device__ __forceinline__ uint_t pk2(float a, float b) {
    return (uint_t)f2b(a) | ((uint_t)f2b(b) << 16);
}

// ---------------- transpose W[K][N] (fp32) -> Wt[N][K] (bf16) ----------------
__global__ __launch_bounds__(256) void k_transpose(const float* __restrict__ in,
                                                   ushort_t* __restrict__ out,
                                                   int K, int Npr) {
    __shared__ float tile[32][33];
    int tx = threadIdx.x & 31, ty = threadIdx.x >> 5;   // ty 0..7
    int kb = blockIdx.y * 32, nb = blockIdx.x * 32;
#pragma unroll
    for (int i = 0; i < 4; i++)
        tile[ty + i * 8][tx] = in[(size_t)(kb + ty + i * 8) * Npr + nb + tx];
    __syncthreads();
#pragma unroll
    for (int i = 0; i < 4; i++)
        out[(size_t)(nb + ty + i * 8) * K + kb + tx] = f2b(tile[tx][ty + i * 8]);
}

// ---------------- pack conv weights tap-major + zero page ----------------
__global__ __launch_bounds__(256) void k_wtrans(const float* __restrict__ cpe_w,
                                                const float* __restrict__ w3,
                                                const float* __restrict__ w5,
                                                const float* __restrict__ w7,
                                                float* __restrict__ wpk) {
    int idx = blockIdx.x * 256 + threadIdx.x;
    if (idx < 4608) {
        int i = idx / 512, c = idx % 512;
        wpk[idx] = cpe_w[c * 9 + i];
    } else if (idx < 5760) {
        int r = idx - 4608; int i = r / 128, c = r % 128;
        wpk[idx] = w3[c * 9 + i];
    } else if (idx < 10560) {
        int r = idx - 5760; int i = r / 192, c = r % 192;
        wpk[idx] = w5[c * 25 + i];
    } else if (idx < 19968) {
        int r = idx - 10560; int i = r / 192, c = r % 192;
        wpk[idx] = w7[c * 49 + i];
    } else if (idx < WPK_TOTAL) {
        wpk[idx] = 0.f;
    }
}

// ---------------- ConvPosEnc: x0 = dwconv3x3(x) + b + x  (all fp32, float4) ----------------
__global__ __launch_bounds__(256) void k_cpe(const float* __restrict__ x,
                                             const float* __restrict__ wpk,
                                             const float* __restrict__ bias,
                                             float* __restrict__ x0) {
    int t = threadIdx.x;
    int tok = t >> 7;            // 2 tokens per block
    int c0 = (t & 127) * 4;
    int bb = blockIdx.y;
    int n = blockIdx.x * 2 + tok;
    int y = n / HW, xx = n % HW;
    const float* xb = x + ((size_t)bb * NTOK) * CDIM + c0;
    const float* zf = wpk + 19968;
    float4 a = *(const float4*)(bias + c0);
#pragma unroll
    for (int i = 0; i < 9; i++) {
        int ky = i / 3 - 1, kx = i % 3 - 1;
        int yy = y + ky, xc = xx + kx;
        bool ok = (unsigned)yy < HW && (unsigned)xc < HW;
        const float* ap = ok ? (xb + (size_t)(yy * HW + xc) * CDIM) : zf;
        float4 d = *(const float4*)ap;
        float4 w = *(const float4*)(wpk + i * 512 + c0);
        a.x += w.x * d.x; a.y += w.y * d.y; a.z += w.z * d.z; a.w += w.w * d.w;
    }
    float4 ctr = *(const float4*)(xb + (size_t)n * CDIM);
    a.x += ctr.x; a.y += ctr.y; a.z += ctr.z; a.w += ctr.w;
    *(float4*)(x0 + ((size_t)bb * NTOK + n) * CDIM + c0) = a;
}

// -------- LayerNorm over C=512: fp32 in -> bf16 out, one wave per row --------
__global__ __launch_bounds__(256) void k_ln(const float* __restrict__ in,
                                            const float* __restrict__ w,
                                            const float* __restrict__ b,
                                            ushort_t* __restrict__ out) {
    int wid = threadIdx.x >> 6, lane = threadIdx.x & 63;
    size_t row = (size_t)blockIdx.x * 4 + wid;
    const float* p = in + row * CDIM + lane * 8;
    float4 v0 = *(const float4*)p;
    float4 v1 = *(const float4*)(p + 4);
    float v[8] = { v0.x, v0.y, v0.z, v0.w, v1.x, v1.y, v1.z, v1.w };
    float s = 0.f, s2 = 0.f;
#pragma unroll
    for (int i = 0; i < 8; i++) { s += v[i]; s2 += v[i] * v[i]; }
#pragma unroll
    for (int m = 1; m < 64; m <<= 1) { s += __shfl_xor(s, m); s2 += __shfl_xor(s2, m); }
    float mean = s * (1.f / CDIM);
    float var = s2 * (1.f / CDIM) - mean * mean;
    float rstd = rsqrtf(var + 1e-6f);
    float4 w0 = *(const float4*)(w + lane * 8);
    float4 w1 = *(const float4*)(w + lane * 8 + 4);
    float4 b0 = *(const float4*)(b + lane * 8);
    float4 b1 = *(const float4*)(b + lane * 8 + 4);
    float wv[8] = { w0.x, w0.y, w0.z, w0.w, w1.x, w1.y, w1.z, w1.w };
    float bv[8] = { b0.x, b0.y, b0.z, b0.w, b1.x, b1.y, b1.z, b1.w };
    float o[8];
#pragma unroll
    for (int i = 0; i < 8; i++) o[i] = (v[i] - mean) * rstd * wv[i] + bv[i];
    uint4 ro;
    ro.x = pk2(o[0], o[1]); ro.y = pk2(o[2], o[3]); ro.z = pk2(o[4], o[5]); ro.w = pk2(o[6], o[7]);
    *(uint4*)(out + row * CDIM + lane * 8) = ro;
}

// ------------- MFMA GEMM: out[M,N] = A[M,K] @ Bt[N,K]^T  (A,Bt bf16) -------------
// EPI 0: store bf16.  EPI 1: +bias +res(fp32), store fp32.  EPI 2: +bias, GELU, store bf16.
template <int EPI>
__global__ __launch_bounds__(256) void k_gemm(const ushort_t* __restrict__ A,
                                              const ushort_t* __restrict__ Bt,
                                              const float* __restrict__ bias,
                                              const float* __restrict__ res,
                                              void* __restrict__ outv,
                                              int M, int Npr, int K) {
    __shared__ ushort_t As[128 * 72];
    __shared__ ushort_t Bs[128 * 72];
    int t = threadIdx.x;
    int m0 = blockIdx.y * 128, n0 = blockIdx.x * 128;
    int wid = t >> 6, lane = t & 63, q = lane >> 4, r16 = lane & 15;
    int wr = wid >> 1, wc = wid & 1;
    f32x4 acc[4][4] = {};
    int rowA = t >> 3, kc = (t & 7) * 8;
    const ushort_t* pAp[4];
    const ushort_t* pBp[4];
#pragma unroll
    for (int p4 = 0; p4 < 4; p4++) {
        int ra = m0 + rowA + p4 * 32; if (ra > M - 1) ra = M - 1;
        pAp[p4] = A + (size_t)ra * K + kc;
        pBp[p4] = Bt + (size_t)(n0 + rowA + p4 * 32) * K + kc;
    }

    for (int k0 = 0; k0 < K; k0 += 64) {
#pragma unroll
        for (int p4 = 0; p4 < 4; p4++) {
            uint4 va = *(const uint4*)(pAp[p4] + k0);
            uint4 vb = *(const uint4*)(pBp[p4] + k0);
            *(uint4*)&As[(rowA + p4 * 32) * 72 + kc] = va;
            *(uint4*)&Bs[(rowA + p4 * 32) * 72 + kc] = vb;
        }
        __syncthreads();
#pragma unroll
        for (int kk = 0; kk < 64; kk += 32) {
            s16x8 a[4], b[4];
#pragma unroll
            for (int i = 0; i < 4; i++) {
                a[i] = *(const s16x8*)&As[(wr * 64 + i * 16 + r16) * 72 + kk + q * 8];
                b[i] = *(const s16x8*)&Bs[(wc * 64 + i * 16 + r16) * 72 + kk + q * 8];
            }
#pragma unroll
            for (int mi = 0; mi < 4; mi++)
#pragma unroll
                for (int ni = 0; ni < 4; ni++)
                    acc[mi][ni] = __builtin_amdgcn_mfma_f32_16x16x32_bf16(a[mi], b[ni], acc[mi][ni], 0, 0, 0);
        }
        __syncthreads();
    }

#pragma unroll
    for (int mi = 0; mi < 4; mi++) {
#pragma unroll
        for (int ni = 0; ni < 4; ni++) {
            int col = n0 + wc * 64 + ni * 16 + r16;
            float bv = 0.f;
            if (EPI != 0) bv = bias[col];
#pragma unroll
            for (int r = 0; r < 4; r++) {
                int row = m0 + wr * 64 + mi * 16 + q * 4 + r;
                if (row >= M) continue;
                float xv = acc[mi][ni][r];
                size_t idx = (size_t)row * Npr + col;
                if (EPI == 0) {
                    ((ushort_t*)outv)[idx] = f2b(xv);
                } else if (EPI == 1) {
                    ((float*)outv)[idx] = xv + bv + res[idx];
                } else {
                    xv += bv;
                    xv = 0.5f * xv * (1.f + erff(xv * 0.70710678118654752f));
                    ((ushort_t*)outv)[idx] = f2b(xv);
                }
            }
        }
    }
}

// ------------- softmax stats over tokens: per (b, channel) max & sum(exp) -------------
__global__ __launch_bounds__(256) void k_softmax_stats(const ushort_t* __restrict__ qkv,
                                                       float* __restrict__ Mx,
                                                       float* __restrict__ Sx) {
    int b = blockIdx.y, c0 = blockIdx.x * 64;
    int ch = threadIdx.x & 63, nt = threadIdx.x >> 6;
    const ushort_t* base = qkv + (size_t)b * NTOK * QKVC + CDIM + c0 + ch;
    __shared__ float red[4][64];
    float mx = -1e30f;
    for (int n = nt; n < NTOK; n += 4) mx = fmaxf(mx, b2f(base[(size_t)n * QKVC]));
    red[nt][ch] = mx;
    __syncthreads();
    if (nt == 0) {
        mx = fmaxf(fmaxf(red[0][ch], red[1][ch]), fmaxf(red[2][ch], red[3][ch]));
        red[0][ch] = mx;
    }
    __syncthreads();
    mx = red[0][ch];
    __syncthreads();
    float s = 0.f;
    for (int n = nt; n < NTOK; n += 4) s += __expf(b2f(base[(size_t)n * QKVC]) - mx);
    red[nt][ch] = s;
    __syncthreads();
    if (nt == 0) {
        s = red[0][ch] + red[1][ch] + red[2][ch] + red[3][ch];
        Mx[b * CDIM + c0 + ch] = mx;
        Sx[b * CDIM + c0 + ch] = s;
    }
}

// ------------- kv[b,h] = scale * softmax(k)^T @ v  (64x64 fp32) -------------
__global__ __launch_bounds__(256) void k_kv(const ushort_t* __restrict__ qkv,
                                            const float* __restrict__ Mx,
                                            const float* __restrict__ Sx,
                                            float* __restrict__ kv) {
    int hd = blockIdx.x, b = blockIdx.y;
    int c0 = hd * CH;
    int t = threadIdx.x, tx = t & 15, ty = t >> 4;
    __shared__ float mx[64];
    __shared__ float ek[8][64];
    __shared__ float vv[8][64];
    if (t < 64) mx[t] = Mx[b * CDIM + c0 + t];
    __syncthreads();
    float acc[4][4] = {};
    const ushort_t* kbase = qkv + (size_t)b * NTOK * QKVC + CDIM + c0;
    const ushort_t* vbase = kbase + CDIM;
    for (int n0 = 0; n0 < NTOK; n0 += 8) {
        for (int idx = t; idx < 512; idx += 256) {
            int r = idx >> 6, ch = idx & 63;
            ek[r][ch] = __expf(b2f(kbase[(size_t)(n0 + r) * QKVC + ch]) - mx[ch]);
            vv[r][ch] = b2f(vbase[(size_t)(n0 + r) * QKVC + ch]);
        }
        __syncthreads();
#pragma unroll
        for (int r = 0; r < 8; r++) {
            float ekv[4], vvv[4];
#pragma unroll
            for (int i = 0; i < 4; i++) ekv[i] = ek[r][ty * 4 + i];
#pragma unroll
            for (int j = 0; j < 4; j++) vvv[j] = vv[r][tx * 4 + j];
#pragma unroll
            for (int i = 0; i < 4; i++)
#pragma unroll
                for (int j = 0; j < 4; j++) acc[i][j] += ekv[i] * vvv[j];
        }
        __syncthreads();
    }
    const float scale = 0.125f;   // Ch^-0.5, folded here
    float* outp = kv + (size_t)(b * NHEAD + hd) * CH * CH;
#pragma unroll
    for (int i = 0; i < 4; i++) {
        float sinv = scale / Sx[b * CDIM + c0 + ty * 4 + i];
#pragma unroll
        for (int j = 0; j < 4; j++)
            outp[(size_t)(ty * 4 + i) * CH + tx * 4 + j] = acc[i][j] * sinv;
    }
}

// ------------- ConvRelPosEnc: grouped depthwise 3/5/7 conv on v -------------
// lane owns 8 channels (uint4 bf16 loads); wave processes 4 tokens; branchless
// boundary via zero-page address select; weights tap-major fp32 from wpk.
__global__ __launch_bounds__(256) void k_convv(const ushort_t* __restrict__ qkv,
                                               const float* __restrict__ wpk,
                                               const float* __restrict__ b3,
                                               const float* __restrict__ b5,
                                               const float* __restrict__ b7,
                                               ushort_t* __restrict__ conv) {
    int t = threadIdx.x;
    int wv = t >> 6, lane = t & 63;
    int bb = blockIdx.y;
    int n0 = blockIdx.x * 16 + wv * 4;
    int ch0 = lane * 8;
    int ks, pad, base, stride; const float* bias;
    if (lane < 16)      { ks = 3; pad = 1; base = 4608 + ch0;          stride = 128; bias = b3 + ch0; }
    else if (lane < 40) { ks = 5; pad = 2; base = 5760 + (ch0 - 128);  stride = 192; bias = b5 + (ch0 - 128); }
    else                { ks = 7; pad = 3; base = 10560 + (ch0 - 320); stride = 192; bias = b7 + (ch0 - 320); }
    int ks2 = ks * ks;
    const ushort_t* vb = qkv + (size_t)bb * NTOK * QKVC + 2 * CDIM + ch0;
    const ushort_t* zp = (const ushort_t*)(wpk + 19968);
    float4 blo = *(const float4*)(bias);
    float4 bhi = *(const float4*)(bias + 4);
    float acc[4][8];
    int ty[4], txx[4];
#pragma unroll
    for (int k4 = 0; k4 < 4; k4++) {
        int n = n0 + k4; ty[k4] = n / HW; txx[k4] = n % HW;
        acc[k4][0] = blo.x; acc[k4][1] = blo.y; acc[k4][2] = blo.z; acc[k4][3] = blo.w;
        acc[k4][4] = bhi.x; acc[k4][5] = bhi.y; acc[k4][6] = bhi.z; acc[k4][7] = bhi.w;
    }
    int ky = -pad, kx = -pad;
    for (int i = 0; i < 49; i++) {
        bool act = i < ks2;
        int ie = act ? i : 0;
        const float* wp = wpk + base + ie * stride;
        float4 wlo = *(const float4*)wp;
        float4 whi = *(const float4*)(wp + 4);
        float w[8] = { wlo.x, wlo.y, wlo.z, wlo.w, whi.x, whi.y, whi.z, whi.w };
#pragma unroll
        for (int k4 = 0; k4 < 4; k4++) {
            int yy = ty[k4] + ky, xc = txx[k4] + kx;
            bool ok = act && (unsigned)yy < HW && (unsigned)xc < HW;
            const ushort_t* ap = ok ? (vb + (size_t)(yy * HW + xc) * QKVC) : zp;
            uint4 d = *(const uint4*)ap;
            float dv[8];
            dv[0] = b2f(d.x & 0xffff); dv[1] = b2f(d.x >> 16);
            dv[2] = b2f(d.y & 0xffff); dv[3] = b2f(d.y >> 16);
            dv[4] = b2f(d.z & 0xffff); dv[5] = b2f(d.z >> 16);
            dv[6] = b2f(d.w & 0xffff); dv[7] = b2f(d.w >> 16);
#pragma unroll
            for (int j = 0; j < 8; j++) acc[k4][j] += w[j] * dv[j];
        }
        kx++; if (kx > pad) { kx = -pad; ky++; }
    }
#pragma unroll
    for (int k4 = 0; k4 < 4; k4++) {
        int n = n0 + k4;
        uint4 o;
        o.x = pk2(acc[k4][0], acc[k4][1]);
        o.y = pk2(acc[k4][2], acc[k4][3]);
        o.z = pk2(acc[k4][4], acc[k4][5]);
        o.w = pk2(acc[k4][6], acc[k4][7]);
        *(uint4*)&conv[((size_t)bb * NTOK + n) * CDIM + ch0] = o;
    }
}

// ------------- attn = q @ kv + q * conv_v  (overwrites conv buffer, bf16) -------------
__global__ __launch_bounds__(256) void k_attn(const ushort_t* __restrict__ qkv,
                                              const float* __restrict__ kv,
                                              ushort_t* __restrict__ conv) {
    int nb = blockIdx.x, hd = blockIdx.y, b = blockIdx.z;
    int t = threadIdx.x, tx = t & 15, ty = t >> 4;   // ty 0..15
    __shared__ float kvl[64 * 64];    // [ck][cv]
    __shared__ float ql[64 * 65];     // [row][ck], padded
    const float* kvsrc = kv + (size_t)(b * NHEAD + hd) * CH * CH;
    for (int idx = t; idx < 4096; idx += 256) kvl[idx] = kvsrc[idx];
    const ushort_t* qbase = qkv + ((size_t)b * NTOK + nb * 64) * QKVC + hd * CH;
    for (int idx = t; idx < 4096; idx += 256) {
        int r = idx >> 6, ck = idx & 63;
        ql[r * 65 + ck] = b2f(qbase[(size_t)r * QKVC + ck]);
    }
    __syncthreads();
    float acc[4][4] = {};
    for (int ck = 0; ck < 64; ck++) {
        float kvr[4];
#pragma unroll
        for (int j = 0; j < 4; j++) kvr[j] = kvl[ck * 64 + tx * 4 + j];
#pragma unroll
        for (int i = 0; i < 4; i++) {
            float qv = ql[(ty + 16 * i) * 65 + ck];
#pragma unroll
            for (int j = 0; j < 4; j++) acc[i][j] += qv * kvr[j];
        }
    }
    size_t obase = (size_t)b * NTOK + nb * 64;
#pragma unroll
    for (int i = 0; i < 4; i++) {
        int row = ty + 16 * i;
        size_t o = (obase + row) * CDIM + hd * CH + tx * 4;
#pragma unroll
        for (int j = 0; j < 4; j++) {
            float qv = ql[row * 65 + tx * 4 + j];
            float cvv = b2f(conv[o + j]);
            conv[o + j] = f2b(acc[i][j] + qv * cvv);
        }
    }
}

// ---------------------------------------------------------------------------
extern "C" void kernel_launch(void* const* d_in, const int* in_sizes, int n_in,
                              void* d_out, int out_size, void* d_ws, size_t ws_size,
                              hipStream_t stream) {
    const float* x     = (const float*)d_in[0];
    const float* cpe_w = (const float*)d_in[3];
    const float* cpe_b = (const float*)d_in[4];
    const float* ln1_w = (const float*)d_in[5];
    const float* ln1_b = (const float*)d_in[6];
    const float* qkv_w = (const float*)d_in[7];
    const float* proj_w = (const float*)d_in[8];
    const float* proj_b = (const float*)d_in[9];
    const float* w3 = (const float*)d_in[10];
    const float* b3 = (const float*)d_in[11];
    const float* w5 = (const float*)d_in[12];
    const float* b5 = (const float*)d_in[13];
    const float* w7 = (const float*)d_in[14];
    const float* b7 = (const float*)d_in[15];
    const float* ln2_w = (const float*)d_in[16];
    const float* ln2_b = (const float*)d_in[17];
    const float* fc1_w = (const float*)d_in[18];
    const float* fc1_b = (const float*)d_in[19];
    const float* fc2_w = (const float*)d_in[20];
    const float* fc2_b = (const float*)d_in[21];
    float* out = (float*)d_out;

    char* p = (char*)d_ws;
    ushort_t* wt_qkv  = (ushort_t*)p; p += (size_t)QKVC * CDIM * 2;
    ushort_t* wt_proj = (ushort_t*)p; p += (size_t)CDIM * CDIM * 2;
    ushort_t* wt_fc1  = (ushort_t*)p; p += (size_t)HID * CDIM * 2;
    ushort_t* wt_fc2  = (ushort_t*)p; p += (size_t)CDIM * HID * 2;
    float* wpk = (float*)p; p += 20480 * 4;   // WPK_TOTAL rounded up
    size_t wt_bytes = (size_t)(p - (char*)d_ws);

    k_transpose<<<dim3(QKVC / 32, CDIM / 32), 256, 0, stream>>>(qkv_w, wt_qkv, CDIM, QKVC);
    k_transpose<<<dim3(CDIM / 32, CDIM / 32), 256, 0, stream>>>(proj_w, wt_proj, CDIM, CDIM);
    k_transpose<<<dim3(HID / 32, CDIM / 32), 256, 0, stream>>>(fc1_w, wt_fc1, CDIM, HID);
    k_transpose<<<dim3(CDIM / 32, HID / 32), 256, 0, stream>>>(fc2_w, wt_fc2, HID, CDIM);
    k_wtrans<<<(WPK_TOTAL + 255) / 256, 256, 0, stream>>>(cpe_w, w3, w5, w7, wpk);

    // per-batch bytes: cur(bf16) + union{conv+qkvb | hid}(bf16) + kv + stats
    const size_t per_b = (size_t)NTOK * CDIM * 2
                       + (size_t)NTOK * HID * 2
                       + (size_t)NHEAD * CH * CH * 4
                       + (size_t)CDIM * 4 * 2;
    int Bc = 16;
    while (Bc > 1 && wt_bytes + (size_t)Bc * per_b > ws_size) Bc >>= 1;

    ushort_t* cur = (ushort_t*)p; p += (size_t)Bc * NTOK * CDIM * 2;
    char* un = p;                 p += (size_t)Bc * NTOK * HID * 2;
    ushort_t* conv = (ushort_t*)un;
    ushort_t* qkvb = (ushort_t*)(un + (size_t)Bc * NTOK * CDIM * 2);
    ushort_t* hid  = (ushort_t*)un;
    float* kvb = (float*)p; p += (size_t)Bc * NHEAD * CH * CH * 4;
    float* Mx  = (float*)p; p += (size_t)Bc * CDIM * 4;
    float* Sx  = (float*)p;

    for (int b0 = 0; b0 < 16; b0 += Bc) {
        int M = Bc * NTOK;
        int gy = (M + 127) / 128;
        const float* xch = x + (size_t)b0 * NTOK * CDIM;
        float* och = out + (size_t)b0 * NTOK * CDIM;
        float* x0 = och;   // fp32 residual backbone lives in the output chunk

        k_cpe<<<dim3(NTOK / 2, Bc), 256, 0, stream>>>(xch, wpk, cpe_b, x0);
        k_ln<<<M / 4, 256, 0, stream>>>(x0, ln1_w, ln1_b, cur);
        k_gemm<0><<<dim3(QKVC / 128, gy), 256, 0, stream>>>(cur, wt_qkv, nullptr, nullptr, qkvb, M, QKVC, CDIM);
        k_softmax_stats<<<dim3(8, Bc), 256, 0, stream>>>(qkvb, Mx, Sx);
        k_kv<<<dim3(NHEAD, Bc), 256, 0, stream>>>(qkvb, Mx, Sx, kvb);
        k_convv<<<dim3(NTOK / 16, Bc), 256, 0, stream>>>(qkvb, wpk, b3, b5, b7, conv);
        k_attn<<<dim3(NTOK / 64, NHEAD, Bc), 256, 0, stream>>>(qkvb, kvb, conv);
        k_gemm<1><<<dim3(CDIM / 128, gy), 256, 0, stream>>>(conv, wt_proj, proj_b, x0, x0, M, CDIM, CDIM);
        k_ln<<<M / 4, 256, 0, stream>>>(x0, ln2_w, ln2_b, cur);
        k_gemm<2><<<dim3(HID / 128, gy), 256, 0, stream>>>(cur, wt_fc1, fc1_b, nullptr, hid, M, HID, CDIM);
        k_gemm<1><<<dim3(CDIM / 128, gy), 256, 0, stream>>>(hid, wt_fc2, fc2_b, x0, och, M, CDIM, HID);
    }
}

// Round 5
// 1347.642 us; speedup vs baseline: 2.7502x; 1.5170x over previous
//
#include <hip/hip_runtime.h>
#include <hip/hip_bf16.h>

typedef unsigned short ushort_t;
typedef unsigned int uint_t;

typedef float f32x4 __attribute__((ext_vector_type(4)));
typedef short s16x8 __attribute__((ext_vector_type(8)));

#define HW 56
#define NTOK 3136           // 56*56
#define CDIM 512
#define NHEAD 8
#define CH 64
#define QKVC 1536
#define HID 2048
#define NSEG 28
#define SEGLEN 112          // NTOK / NSEG

// packed tap-major weight buffer layout (floats):
// [0,4608)      cpe 3x3:  [i*512 + c]           i<9,  c<512
// [4608,5760)   crpe 3x3: [4608 + i*128 + c]    i<9,  c<128
// [5760,10560)  crpe 5x5: [5760 + i*192 + c]    i<25, c<192
// [10560,19968) crpe 7x7: [10560 + i*192 + c]   i<49, c<192
// [19968,19976) zeros (zero-page for OOB loads)
#define WPK_TOTAL 19976

__device__ __forceinline__ float b2f(ushort_t u) {
    union { uint_t i; float f; } cv; cv.i = ((uint_t)u) << 16; return cv.f;
}
__device__ __forceinline__ ushort_t f2b(float f) {
    union { __hip_bfloat16 h; ushort_t u; } cv; cv.h = __float2bfloat16(f); return cv.u;
}
__device__ __forceinline__ uint_t pk2(float a, float b) {
    return (uint_t)f2b(a) | ((uint_t)f2b(b) << 16);
}

// ---------------- transpose W[K][N] (fp32) -> Wt[N][K] (bf16) ----------------
__global__ __launch_bounds__(256) void k_transpose(const float* __restrict__ in,
                                                   ushort_t* __restrict__ out,
                                                   int K, int Npr) {
    __shared__ float tile[32][33];
    int tx = threadIdx.x & 31, ty = threadIdx.x >> 5;   // ty 0..7
    int kb = blockIdx.y * 32, nb = blockIdx.x * 32;
#pragma unroll
    for (int i = 0; i < 4; i++)
        tile[ty + i * 8][tx] = in[(size_t)(kb + ty + i * 8) * Npr + nb + tx];
    __syncthreads();
#pragma unroll
    for (int i = 0; i < 4; i++)
        out[(size_t)(nb + ty + i * 8) * K + kb + tx] = f2b(tile[tx][ty + i * 8]);
}

// ---------------- pack conv weights tap-major + zero page ----------------
__global__ __launch_bounds__(256) void k_wtrans(const float* __restrict__ cpe_w,
                                                const float* __restrict__ w3,
                                                const float* __restrict__ w5,
                                                const float* __restrict__ w7,
                                                float* __restrict__ wpk) {
    int idx = blockIdx.x * 256 + threadIdx.x;
    if (idx < 4608) {
        int i = idx / 512, c = idx % 512;
        wpk[idx] = cpe_w[c * 9 + i];
    } else if (idx < 5760) {
        int r = idx - 4608; int i = r / 128, c = r % 128;
        wpk[idx] = w3[c * 9 + i];
    } else if (idx < 10560) {
        int r = idx - 5760; int i = r / 192, c = r % 192;
        wpk[idx] = w5[c * 25 + i];
    } else if (idx < 19968) {
        int r = idx - 10560; int i = r / 192, c = r % 192;
        wpk[idx] = w7[c * 49 + i];
    } else if (idx < WPK_TOTAL) {
        wpk[idx] = 0.f;
    }
}

// ---------------- ConvPosEnc: x0 = dwconv3x3(x) + b + x  (all fp32, float4) ----------------
__global__ __launch_bounds__(256) void k_cpe(const float* __restrict__ x,
                                             const float* __restrict__ wpk,
                                             const float* __restrict__ bias,
                                             float* __restrict__ x0) {
    int t = threadIdx.x;
    int tok = t >> 7;            // 2 tokens per block
    int c0 = (t & 127) * 4;
    int bb = blockIdx.y;
    int n = blockIdx.x * 2 + tok;
    int y = n / HW, xx = n % HW;
    const float* xb = x + ((size_t)bb * NTOK) * CDIM + c0;
    const float* zf = wpk + 19968;
    float4 a = *(const float4*)(bias + c0);
#pragma unroll
    for (int i = 0; i < 9; i++) {
        int ky = i / 3 - 1, kx = i % 3 - 1;
        int yy = y + ky, xc = xx + kx;
        bool ok = (unsigned)yy < HW && (unsigned)xc < HW;
        const float* ap = ok ? (xb + (size_t)(yy * HW + xc) * CDIM) : zf;
        float4 d = *(const float4*)ap;
        float4 w = *(const float4*)(wpk + i * 512 + c0);
        a.x += w.x * d.x; a.y += w.y * d.y; a.z += w.z * d.z; a.w += w.w * d.w;
    }
    float4 ctr = *(const float4*)(xb + (size_t)n * CDIM);
    a.x += ctr.x; a.y += ctr.y; a.z += ctr.z; a.w += ctr.w;
    *(float4*)(x0 + ((size_t)bb * NTOK + n) * CDIM + c0) = a;
}

// -------- LayerNorm over C=512: fp32 in -> bf16 out, one wave per row --------
__global__ __launch_bounds__(256) void k_ln(const float* __restrict__ in,
                                            const float* __restrict__ w,
                                            const float* __restrict__ b,
                                            ushort_t* __restrict__ out) {
    int wid = threadIdx.x >> 6, lane = threadIdx.x & 63;
    size_t row = (size_t)blockIdx.x * 4 + wid;
    const float* p = in + row * CDIM + lane * 8;
    float4 v0 = *(const float4*)p;
    float4 v1 = *(const float4*)(p + 4);
    float v[8] = { v0.x, v0.y, v0.z, v0.w, v1.x, v1.y, v1.z, v1.w };
    float s = 0.f, s2 = 0.f;
#pragma unroll
    for (int i = 0; i < 8; i++) { s += v[i]; s2 += v[i] * v[i]; }
#pragma unroll
    for (int m = 1; m < 64; m <<= 1) { s += __shfl_xor(s, m); s2 += __shfl_xor(s2, m); }
    float mean = s * (1.f / CDIM);
    float var = s2 * (1.f / CDIM) - mean * mean;
    float rstd = rsqrtf(var + 1e-6f);
    float4 w0 = *(const float4*)(w + lane * 8);
    float4 w1 = *(const float4*)(w + lane * 8 + 4);
    float4 b0 = *(const float4*)(b + lane * 8);
    float4 b1 = *(const float4*)(b + lane * 8 + 4);
    float wv[8] = { w0.x, w0.y, w0.z, w0.w, w1.x, w1.y, w1.z, w1.w };
    float bv[8] = { b0.x, b0.y, b0.z, b0.w, b1.x, b1.y, b1.z, b1.w };
    float o[8];
#pragma unroll
    for (int i = 0; i < 8; i++) o[i] = (v[i] - mean) * rstd * wv[i] + bv[i];
    uint4 ro;
    ro.x = pk2(o[0], o[1]); ro.y = pk2(o[2], o[3]); ro.z = pk2(o[4], o[5]); ro.w = pk2(o[6], o[7]);
    *(uint4*)(out + row * CDIM + lane * 8) = ro;
}

// ------------- MFMA GEMM: out[M,N] = A[M,K] @ Bt[N,K]^T  (A,Bt bf16) -------------
// EPI 0: store bf16.  EPI 1: +bias +res(fp32), store fp32.  EPI 2: +bias, GELU, store bf16.
template <int EPI>
__global__ __launch_bounds__(256) void k_gemm(const ushort_t* __restrict__ A,
                                              const ushort_t* __restrict__ Bt,
                                              const float* __restrict__ bias,
                                              const float* __restrict__ res,
                                              void* __restrict__ outv,
                                              int M, int Npr, int K) {
    __shared__ ushort_t As[128 * 72];
    __shared__ ushort_t Bs[128 * 72];
    int t = threadIdx.x;
    int m0 = blockIdx.y * 128, n0 = blockIdx.x * 128;
    int wid = t >> 6, lane = t & 63, q = lane >> 4, r16 = lane & 15;
    int wr = wid >> 1, wc = wid & 1;
    f32x4 acc[4][4] = {};
    int rowA = t >> 3, kc = (t & 7) * 8;
    const ushort_t* pAp[4];
    const ushort_t* pBp[4];
#pragma unroll
    for (int p4 = 0; p4 < 4; p4++) {
        int ra = m0 + rowA + p4 * 32; if (ra > M - 1) ra = M - 1;
        pAp[p4] = A + (size_t)ra * K + kc;
        pBp[p4] = Bt + (size_t)(n0 + rowA + p4 * 32) * K + kc;
    }

    for (int k0 = 0; k0 < K; k0 += 64) {
#pragma unroll
        for (int p4 = 0; p4 < 4; p4++) {
            uint4 va = *(const uint4*)(pAp[p4] + k0);
            uint4 vb = *(const uint4*)(pBp[p4] + k0);
            *(uint4*)&As[(rowA + p4 * 32) * 72 + kc] = va;
            *(uint4*)&Bs[(rowA + p4 * 32) * 72 + kc] = vb;
        }
        __syncthreads();
#pragma unroll
        for (int kk = 0; kk < 64; kk += 32) {
            s16x8 a[4], b[4];
#pragma unroll
            for (int i = 0; i < 4; i++) {
                a[i] = *(const s16x8*)&As[(wr * 64 + i * 16 + r16) * 72 + kk + q * 8];
                b[i] = *(const s16x8*)&Bs[(wc * 64 + i * 16 + r16) * 72 + kk + q * 8];
            }
#pragma unroll
            for (int mi = 0; mi < 4; mi++)
#pragma unroll
                for (int ni = 0; ni < 4; ni++)
                    acc[mi][ni] = __builtin_amdgcn_mfma_f32_16x16x32_bf16(a[mi], b[ni], acc[mi][ni], 0, 0, 0);
        }
        __syncthreads();
    }

#pragma unroll
    for (int mi = 0; mi < 4; mi++) {
#pragma unroll
        for (int ni = 0; ni < 4; ni++) {
            int col = n0 + wc * 64 + ni * 16 + r16;
            float bv = 0.f;
            if (EPI != 0) bv = bias[col];
#pragma unroll
            for (int r = 0; r < 4; r++) {
                int row = m0 + wr * 64 + mi * 16 + q * 4 + r;
                if (row >= M) continue;
                float xv = acc[mi][ni][r];
                size_t idx = (size_t)row * Npr + col;
                if (EPI == 0) {
                    ((ushort_t*)outv)[idx] = f2b(xv);
                } else if (EPI == 1) {
                    ((float*)outv)[idx] = xv + bv + res[idx];
                } else {
                    xv += bv;
                    xv = 0.5f * xv * (1.f + erff(xv * 0.70710678118654752f));
                    ((ushort_t*)outv)[idx] = f2b(xv);
                }
            }
        }
    }
}

// ------------- softmax phase A: per (b, cblk, seg) partial max & sum(exp) -------------
// mxp/ssp layout: [(b*512 + gc)*NSEG + seg]
__global__ __launch_bounds__(256) void k_sm_part(const ushort_t* __restrict__ qkv,
                                                 float* __restrict__ mxp,
                                                 float* __restrict__ ssp) {
    int cblk = blockIdx.x, seg = blockIdx.y, b = blockIdx.z;
    int ch = threadIdx.x & 63, nt = threadIdx.x >> 6;
    int c0 = cblk * 64;
    const ushort_t* base = qkv + (size_t)b * NTOK * QKVC + CDIM + c0 + ch;
    int nbeg = seg * SEGLEN, nend = nbeg + SEGLEN;
    __shared__ float red[4][64];
    float mx = -1e30f;
    for (int n = nbeg + nt; n < nend; n += 4) mx = fmaxf(mx, b2f(base[(size_t)n * QKVC]));
    red[nt][ch] = mx;
    __syncthreads();
    mx = fmaxf(fmaxf(red[0][ch], red[1][ch]), fmaxf(red[2][ch], red[3][ch]));
    __syncthreads();
    float s = 0.f;
    for (int n = nbeg + nt; n < nend; n += 4) s += __expf(b2f(base[(size_t)n * QKVC]) - mx);
    red[nt][ch] = s;
    __syncthreads();
    if (nt == 0) {
        s = red[0][ch] + red[1][ch] + red[2][ch] + red[3][ch];
        size_t o = ((size_t)b * CDIM + c0 + ch) * NSEG + seg;
        mxp[o] = mx;
        ssp[o] = s;
    }
}

// ------------- softmax phase B: merge NSEG partials (log-sum-exp) -------------
__global__ __launch_bounds__(512) void k_sm_red(const float* __restrict__ mxp,
                                                const float* __restrict__ ssp,
                                                float* __restrict__ Mx,
                                                float* __restrict__ Sx) {
    int b = blockIdx.x, c = threadIdx.x;
    const float* mp = mxp + ((size_t)b * CDIM + c) * NSEG;
    const float* sp = ssp + ((size_t)b * CDIM + c) * NSEG;
    float m = -1e30f;
#pragma unroll 4
    for (int s = 0; s < NSEG; s++) m = fmaxf(m, mp[s]);
    float S = 0.f;
#pragma unroll 4
    for (int s = 0; s < NSEG; s++) S += sp[s] * __expf(mp[s] - m);
    Mx[b * CDIM + c] = m;
    Sx[b * CDIM + c] = S;
}

// ------------- kv partial: seg-chunk of softmax(k)^T @ v  (64x64 fp32) -------------
// kvpart layout: [((b*NHEAD + hd)*NSEG + seg)*4096 + (ck*64 + cv)]
__global__ __launch_bounds__(256) void k_kv_part(const ushort_t* __restrict__ qkv,
                                                 const float* __restrict__ Mx,
                                                 float* __restrict__ kvpart) {
    int hd = blockIdx.x, seg = blockIdx.y, b = blockIdx.z;
    int c0 = hd * CH;
    int t = threadIdx.x, tx = t & 15, ty = t >> 4;
    __shared__ float mx[64];
    __shared__ float ek[8][64];
    __shared__ float vv[8][64];
    if (t < 64) mx[t] = Mx[b * CDIM + c0 + t];
    __syncthreads();
    float acc[4][4] = {};
    const ushort_t* kbase = qkv + (size_t)b * NTOK * QKVC + CDIM + c0;
    const ushort_t* vbase = kbase + CDIM;
    int nbeg = seg * SEGLEN;
    for (int n0 = nbeg; n0 < nbeg + SEGLEN; n0 += 8) {
        for (int idx = t; idx < 512; idx += 256) {
            int r = idx >> 6, ch = idx & 63;
            ek[r][ch] = __expf(b2f(kbase[(size_t)(n0 + r) * QKVC + ch]) - mx[ch]);
            vv[r][ch] = b2f(vbase[(size_t)(n0 + r) * QKVC + ch]);
        }
        __syncthreads();
#pragma unroll
        for (int r = 0; r < 8; r++) {
            float ekv[4], vvv[4];
#pragma unroll
            for (int i = 0; i < 4; i++) ekv[i] = ek[r][ty * 4 + i];
#pragma unroll
            for (int j = 0; j < 4; j++) vvv[j] = vv[r][tx * 4 + j];
#pragma unroll
            for (int i = 0; i < 4; i++)
#pragma unroll
                for (int j = 0; j < 4; j++) acc[i][j] += ekv[i] * vvv[j];
        }
        __syncthreads();
    }
    float* outp = kvpart + (((size_t)(b * NHEAD + hd)) * NSEG + seg) * 4096;
#pragma unroll
    for (int i = 0; i < 4; i++)
#pragma unroll
        for (int j = 0; j < 4; j++)
            outp[(size_t)(ty * 4 + i) * CH + tx * 4 + j] = acc[i][j];
}

// ------------- kv reduce: sum NSEG partials, fold scale/Sx -------------
__global__ __launch_bounds__(256) void k_kv_red(const float* __restrict__ kvpart,
                                                const float* __restrict__ Sx,
                                                float* __restrict__ kv) {
    int quad = blockIdx.x, hd = blockIdx.y, b = blockIdx.z;
    int bh = b * NHEAD + hd;
    int t = threadIdx.x;
    const float* basep = kvpart + ((size_t)bh * NSEG) * 4096 + quad * 1024;
    const float scale = 0.125f;   // Ch^-0.5
#pragma unroll
    for (int k = 0; k < 4; k++) {
        int e = k * 256 + t;
        float s = 0.f;
        for (int sg = 0; sg < NSEG; sg++) s += basep[(size_t)sg * 4096 + e];
        int ck = (quad * 1024 + e) >> 6;
        float sinv = scale / Sx[b * CDIM + hd * CH + ck];
        kv[(size_t)bh * 4096 + quad * 1024 + e] = s * sinv;
    }
}

// ------------- ConvRelPosEnc: grouped depthwise 3/5/7 conv on v -------------
__global__ __launch_bounds__(256) void k_convv(const ushort_t* __restrict__ qkv,
                                               const float* __restrict__ wpk,
                                               const float* __restrict__ b3,
                                               const float* __restrict__ b5,
                                               const float* __restrict__ b7,
                                               ushort_t* __restrict__ conv) {
    int t = threadIdx.x;
    int wv = t >> 6, lane = t & 63;
    int bb = blockIdx.y;
    int n0 = blockIdx.x * 16 + wv * 4;
    int ch0 = lane * 8;
    int ks, pad, base, stride; const float* bias;
    if (lane < 16)      { ks = 3; pad = 1; base = 4608 + ch0;          stride = 128; bias = b3 + ch0; }
    else if (lane < 40) { ks = 5; pad = 2; base = 5760 + (ch0 - 128);  stride = 192; bias = b5 + (ch0 - 128); }
    else                { ks = 7; pad = 3; base = 10560 + (ch0 - 320); stride = 192; bias = b7 + (ch0 - 320); }
    int ks2 = ks * ks;
    const ushort_t* vb = qkv + (size_t)bb * NTOK * QKVC + 2 * CDIM + ch0;
    const ushort_t* zp = (const ushort_t*)(wpk + 19968);
    float4 blo = *(const float4*)(bias);
    float4 bhi = *(const float4*)(bias + 4);
    float acc[4][8];
    int ty[4], txx[4];
#pragma unroll
    for (int k4 = 0; k4 < 4; k4++) {
        int n = n0 + k4; ty[k4] = n / HW; txx[k4] = n % HW;
        acc[k4][0] = blo.x; acc[k4][1] = blo.y; acc[k4][2] = blo.z; acc[k4][3] = blo.w;
        acc[k4][4] = bhi.x; acc[k4][5] = bhi.y; acc[k4][6] = bhi.z; acc[k4][7] = bhi.w;
    }
    int ky = -pad, kx = -pad;
    for (int i = 0; i < 49; i++) {
        bool act = i < ks2;
        int ie = act ? i : 0;
        const float* wp = wpk + base + ie * stride;
        float4 wlo = *(const float4*)wp;
        float4 whi = *(const float4*)(wp + 4);
        float w[8] = { wlo.x, wlo.y, wlo.z, wlo.w, whi.x, whi.y, whi.z, whi.w };
#pragma unroll
        for (int k4 = 0; k4 < 4; k4++) {
            int yy = ty[k4] + ky, xc = txx[k4] + kx;
            bool ok = act && (unsigned)yy < HW && (unsigned)xc < HW;
            const ushort_t* ap = ok ? (vb + (size_t)(yy * HW + xc) * QKVC) : zp;
            uint4 d = *(const uint4*)ap;
            float dv[8];
            dv[0] = b2f(d.x & 0xffff); dv[1] = b2f(d.x >> 16);
            dv[2] = b2f(d.y & 0xffff); dv[3] = b2f(d.y >> 16);
            dv[4] = b2f(d.z & 0xffff); dv[5] = b2f(d.z >> 16);
            dv[6] = b2f(d.w & 0xffff); dv[7] = b2f(d.w >> 16);
#pragma unroll
            for (int j = 0; j < 8; j++) acc[k4][j] += w[j] * dv[j];
        }
        kx++; if (kx > pad) { kx = -pad; ky++; }
    }
#pragma unroll
    for (int k4 = 0; k4 < 4; k4++) {
        int n = n0 + k4;
        uint4 o;
        o.x = pk2(acc[k4][0], acc[k4][1]);
        o.y = pk2(acc[k4][2], acc[k4][3]);
        o.z = pk2(acc[k4][4], acc[k4][5]);
        o.w = pk2(acc[k4][6], acc[k4][7]);
        *(uint4*)&conv[((size_t)bb * NTOK + n) * CDIM + ch0] = o;
    }
}

// ------------- attn = q @ kv + q * conv_v  (overwrites conv buffer, bf16) -------------
__global__ __launch_bounds__(256) void k_attn(const ushort_t* __restrict__ qkv,
                                              const float* __restrict__ kv,
                                              ushort_t* __restrict__ conv) {
    int nb = blockIdx.x, hd = blockIdx.y, b = blockIdx.z;
    int t = threadIdx.x, tx = t & 15, ty = t >> 4;   // ty 0..15
    __shared__ float kvl[64 * 64];    // [ck][cv]
    __shared__ float ql[64 * 65];     // [row][ck], padded
    const float* kvsrc = kv + (size_t)(b * NHEAD + hd) * CH * CH;
    for (int idx = t; idx < 4096; idx += 256) kvl[idx] = kvsrc[idx];
    const ushort_t* qbase = qkv + ((size_t)b * NTOK + nb * 64) * QKVC + hd * CH;
    for (int idx = t; idx < 4096; idx += 256) {
        int r = idx >> 6, ck = idx & 63;
        ql[r * 65 + ck] = b2f(qbase[(size_t)r * QKVC + ck]);
    }
    __syncthreads();
    float acc[4][4] = {};
    for (int ck = 0; ck < 64; ck++) {
        float kvr[4];
#pragma unroll
        for (int j = 0; j < 4; j++) kvr[j] = kvl[ck * 64 + tx * 4 + j];
#pragma unroll
        for (int i = 0; i < 4; i++) {
            float qv = ql[(ty + 16 * i) * 65 + ck];
#pragma unroll
            for (int j = 0; j < 4; j++) acc[i][j] += qv * kvr[j];
        }
    }
    size_t obase = (size_t)b * NTOK + nb * 64;
#pragma unroll
    for (int i = 0; i < 4; i++) {
        int row = ty + 16 * i;
        size_t o = (obase + row) * CDIM + hd * CH + tx * 4;
#pragma unroll
        for (int j = 0; j < 4; j++) {
            float qv = ql[row * 65 + tx * 4 + j];
            float cvv = b2f(conv[o + j]);
            conv[o + j] = f2b(acc[i][j] + qv * cvv);
        }
    }
}

// ---------------------------------------------------------------------------
extern "C" void kernel_launch(void* const* d_in, const int* in_sizes, int n_in,
                              void* d_out, int out_size, void* d_ws, size_t ws_size,
                              hipStream_t stream) {
    const float* x     = (const float*)d_in[0];
    const float* cpe_w = (const float*)d_in[3];
    const float* cpe_b = (const float*)d_in[4];
    const float* ln1_w = (const float*)d_in[5];
    const float* ln1_b = (const float*)d_in[6];
    const float* qkv_w = (const float*)d_in[7];
    const float* proj_w = (const float*)d_in[8];
    const float* proj_b = (const float*)d_in[9];
    const float* w3 = (const float*)d_in[10];
    const float* b3 = (const float*)d_in[11];
    const float* w5 = (const float*)d_in[12];
    const float* b5 = (const float*)d_in[13];
    const float* w7 = (const float*)d_in[14];
    const float* b7 = (const float*)d_in[15];
    const float* ln2_w = (const float*)d_in[16];
    const float* ln2_b = (const float*)d_in[17];
    const float* fc1_w = (const float*)d_in[18];
    const float* fc1_b = (const float*)d_in[19];
    const float* fc2_w = (const float*)d_in[20];
    const float* fc2_b = (const float*)d_in[21];
    float* out = (float*)d_out;

    char* p = (char*)d_ws;
    ushort_t* wt_qkv  = (ushort_t*)p; p += (size_t)QKVC * CDIM * 2;
    ushort_t* wt_proj = (ushort_t*)p; p += (size_t)CDIM * CDIM * 2;
    ushort_t* wt_fc1  = (ushort_t*)p; p += (size_t)HID * CDIM * 2;
    ushort_t* wt_fc2  = (ushort_t*)p; p += (size_t)CDIM * HID * 2;
    float* wpk = (float*)p; p += 20480 * 4;   // WPK_TOTAL rounded up
    size_t wt_bytes = (size_t)(p - (char*)d_ws);

    k_transpose<<<dim3(QKVC / 32, CDIM / 32), 256, 0, stream>>>(qkv_w, wt_qkv, CDIM, QKVC);
    k_transpose<<<dim3(CDIM / 32, CDIM / 32), 256, 0, stream>>>(proj_w, wt_proj, CDIM, CDIM);
    k_transpose<<<dim3(HID / 32, CDIM / 32), 256, 0, stream>>>(fc1_w, wt_fc1, CDIM, HID);
    k_transpose<<<dim3(CDIM / 32, HID / 32), 256, 0, stream>>>(fc2_w, wt_fc2, HID, CDIM);
    k_wtrans<<<(WPK_TOTAL + 255) / 256, 256, 0, stream>>>(cpe_w, w3, w5, w7, wpk);

    // per-batch bytes
    const size_t per_b = (size_t)NTOK * CDIM * 2               // cur
                       + (size_t)NTOK * HID * 2                // union{conv+qkvb | hid}
                       + (size_t)NHEAD * CH * CH * 4           // kv
                       + (size_t)NHEAD * NSEG * 4096 * 4       // kvpart
                       + (size_t)CDIM * 4 * 2                  // Mx, Sx
                       + (size_t)CDIM * NSEG * 4 * 2;          // mxp, ssp
    int Bc = 16;
    while (Bc > 1 && wt_bytes + (size_t)Bc * per_b > ws_size) Bc >>= 1;

    ushort_t* cur = (ushort_t*)p; p += (size_t)Bc * NTOK * CDIM * 2;
    char* un = p;                 p += (size_t)Bc * NTOK * HID * 2;
    ushort_t* conv = (ushort_t*)un;
    ushort_t* qkvb = (ushort_t*)(un + (size_t)Bc * NTOK * CDIM * 2);
    ushort_t* hid  = (ushort_t*)un;
    float* kvb    = (float*)p; p += (size_t)Bc * NHEAD * CH * CH * 4;
    float* kvpart = (float*)p; p += (size_t)Bc * NHEAD * NSEG * 4096 * 4;
    float* Mx  = (float*)p; p += (size_t)Bc * CDIM * 4;
    float* Sx  = (float*)p; p += (size_t)Bc * CDIM * 4;
    float* mxp = (float*)p; p += (size_t)Bc * CDIM * NSEG * 4;
    float* ssp = (float*)p;

    for (int b0 = 0; b0 < 16; b0 += Bc) {
        int M = Bc * NTOK;
        int gy = (M + 127) / 128;
        const float* xch = x + (size_t)b0 * NTOK * CDIM;
        float* och = out + (size_t)b0 * NTOK * CDIM;
        float* x0 = och;   // fp32 residual backbone lives in the output chunk

        k_cpe<<<dim3(NTOK / 2, Bc), 256, 0, stream>>>(xch, wpk, cpe_b, x0);
        k_ln<<<M / 4, 256, 0, stream>>>(x0, ln1_w, ln1_b, cur);
        k_gemm<0><<<dim3(QKVC / 128, gy), 256, 0, stream>>>(cur, wt_qkv, nullptr, nullptr, qkvb, M, QKVC, CDIM);
        k_sm_part<<<dim3(8, NSEG, Bc), 256, 0, stream>>>(qkvb, mxp, ssp);
        k_sm_red<<<Bc, 512, 0, stream>>>(mxp, ssp, Mx, Sx);
        k_kv_part<<<dim3(NHEAD, NSEG, Bc), 256, 0, stream>>>(qkvb, Mx, kvpart);
        k_kv_red<<<dim3(4, NHEAD, Bc), 256, 0, stream>>>(kvpart, Sx, kvb);
        k_convv<<<dim3(NTOK / 16, Bc), 256, 0, stream>>>(qkvb, wpk, b3, b5, b7, conv);
        k_attn<<<dim3(NTOK / 64, NHEAD, Bc), 256, 0, stream>>>(qkvb, kvb, conv);
        k_gemm<1><<<dim3(CDIM / 128, gy), 256, 0, stream>>>(conv, wt_proj, proj_b, x0, x0, M, CDIM, CDIM);
        k_ln<<<M / 4, 256, 0, stream>>>(x0, ln2_w, ln2_b, cur);
        k_gemm<2><<<dim3(HID / 128, gy), 256, 0, stream>>>(cur, wt_fc1, fc1_b, nullptr, hid, M, HID, CDIM);
        k_gemm<1><<<dim3(CDIM / 128, gy), 256, 0, stream>>>(hid, wt_fc2, fc2_b, x0, och, M, CDIM, HID);
    }
}